// Round 1
// baseline (505.781 us; speedup 1.0000x reference)
//
#include <hip/hip_runtime.h>
#include <hip/hip_bf16.h>

// SS2D fused pipeline for MI355X (gfx950). All fp32.
// Stages: K1 in_proj(+silu z) -> K2 dwconv3x3+silu(+transposed copy) ->
// K3 x_dbl proj -> K4 selective scan (16 lanes per scan, lane=state n) ->
// K5a cross-merge -> K5b LayerNorm+gate+out_proj.

#define B_   8
#define H_   48
#define W_   48
#define DM   96
#define DIN  192
#define NST  16
#define RNK  6
#define KD   4
#define L_   (H_*W_)      // 2304

// ---------------------------------------------------------------- K1: in_proj
// xz[b,l,e] = sum_c x[b,l,c] * w[e,c];  e<192 -> xc_pre, e>=192 -> silu -> z
__global__ __launch_bounds__(256) void k1_inproj(
    const float* __restrict__ x, const float* __restrict__ w,
    float* __restrict__ xc_pre, float* __restrict__ z_silu) {
  __shared__ float xs[16][100];                 // 16 rows x 96, pad to 100 (16B-mult)
  const int t = threadIdx.x;
  const long row0 = (long)blockIdx.x * 16;      // row = b*L + l
  for (int idx = t; idx < 16*96; idx += 256) {
    int r = idx / 96, c = idx % 96;
    xs[r][c] = x[(row0 + r)*96 + c];
  }
  __syncthreads();
  for (int u = t; u < 2*DIN; u += 256) {        // u = output channel e
    float acc[16];
    #pragma unroll
    for (int r = 0; r < 16; ++r) acc[r] = 0.f;
    const float4* wrow = (const float4*)(w + u*96);
    #pragma unroll 4
    for (int cq = 0; cq < 24; ++cq) {
      float4 w4 = wrow[cq];
      #pragma unroll
      for (int r = 0; r < 16; ++r) {
        float4 x4 = *((const float4*)&xs[r][cq*4]);
        acc[r] = fmaf(w4.x,x4.x, fmaf(w4.y,x4.y, fmaf(w4.z,x4.z, fmaf(w4.w,x4.w, acc[r]))));
      }
    }
    if (u < DIN) {
      #pragma unroll
      for (int r = 0; r < 16; ++r) xc_pre[(row0 + r)*DIN + u] = acc[r];
    } else {
      #pragma unroll
      for (int r = 0; r < 16; ++r) {
        float v = acc[r];
        z_silu[(row0 + r)*DIN + (u - DIN)] = v / (1.f + __expf(-v));
      }
    }
  }
}

// ------------------------------------------------- K2: depthwise conv + silu
// reads xc_pre (B,L,Din); writes xc (B,Din,L) row-major and xT (B,Din,L) col-major
__global__ __launch_bounds__(256) void k2_conv(
    const float* __restrict__ xc_pre, const float* __restrict__ cw,
    const float* __restrict__ cb, float* __restrict__ xc, float* __restrict__ xT) {
  const int bid = blockIdx.x;
  const int tile = bid % 9; const int dc = (bid/9) % 6; const int b = bid / 54;
  const int h0 = (tile/3)*16, w0 = (tile%3)*16, d0 = dc*32;
  __shared__ float tin[32*325];                 // [d2][hh*18+ww], slice stride 325
  __shared__ float tt[16][17];
  const int t = threadIdx.x;
  for (int idx = t; idx < 32*18*18; idx += 256) {
    int d2 = idx & 31; int rest = idx >> 5; int ww = rest % 18; int hh = rest / 18;
    int h = h0 + hh - 1, w = w0 + ww - 1;
    float v = 0.f;
    if (h >= 0 && h < H_ && w >= 0 && w < W_)
      v = xc_pre[((long)b*L_ + h*W_ + w)*DIN + d0 + d2];
    tin[d2*325 + hh*18 + ww] = v;
  }
  __syncthreads();
  const int hh = t >> 4, ww = t & 15;
  for (int d2 = 0; d2 < 32; ++d2) {
    const int d = d0 + d2;
    float acc = cb[d];
    const float* k9 = &cw[d*9];
    const float* base = &tin[d2*325];
    #pragma unroll
    for (int i = 0; i < 3; ++i)
      #pragma unroll
      for (int j = 0; j < 3; ++j)
        acc = fmaf(base[(hh+i)*18 + ww + j], k9[i*3+j], acc);
    float s = acc / (1.f + __expf(-acc));       // silu
    xc[((long)b*DIN + d)*L_ + (h0+hh)*W_ + w0 + ww] = s;
    __syncthreads();
    tt[hh][ww] = s;
    __syncthreads();
    float s2 = tt[t & 15][t >> 4];              // (h'=t&15, w'=t>>4)
    xT[((long)b*DIN + d)*L_ + (w0 + (t>>4))*H_ + h0 + (t & 15)] = s2;
  }
}

// ----------------------------------------------------------- K3: x_dbl proj
// out[c,l] = sum_d xs[k][d,l] * xpw[k,c,d]; c<6 -> dts_low, <22 -> Bs, else Cs
__global__ __launch_bounds__(256) void k3_xdbl(
    const float* __restrict__ xc, const float* __restrict__ xT,
    const float* __restrict__ xpw, float* __restrict__ dts_low,
    float* __restrict__ Bs, float* __restrict__ Cs) {
  const int bid = blockIdx.x;
  const int lt = bid % 72; const int k = (bid/72) & 3; const int b = bid / 288;
  const int l0 = lt * 32;
  __shared__ float xtile[DIN*32];               // [d][j], row stride 32 (128B)
  __shared__ float wl[38*193];                  // [c][d] padded
  const float* src = (k & 1) ? xT : xc;
  const bool flip = k >= 2;
  const int t = threadIdx.x;
  for (int idx = t; idx < DIN*32; idx += 256) {
    int d = idx >> 5, j = idx & 31;
    int pos = flip ? (L_-1 - (l0+j)) : (l0+j);
    xtile[d*32 + j] = src[((long)b*DIN + d)*L_ + pos];
  }
  for (int idx = t; idx < 38*DIN; idx += 256) {
    int c = idx / DIN, d = idx % DIN;
    wl[c*193 + d] = xpw[(k*38 + c)*DIN + d];
  }
  __syncthreads();
  for (int u = t; u < 38*8; u += 256) {         // unit = (c, jq)
    int jq = u & 7, c = u >> 3;
    float4 acc = {0.f,0.f,0.f,0.f};
    for (int d = 0; d < DIN; ++d) {
      float wv = wl[c*193 + d];
      float4 x4 = *((const float4*)&xtile[d*32 + jq*4]);
      acc.x = fmaf(wv, x4.x, acc.x); acc.y = fmaf(wv, x4.y, acc.y);
      acc.z = fmaf(wv, x4.z, acc.z); acc.w = fmaf(wv, x4.w, acc.w);
    }
    const int l = l0 + jq*4;
    if (c < 6)
      *((float4*)&dts_low[((long)(b*KD + k)*RNK + c)*L_ + l]) = acc;
    else if (c < 22)
      *((float4*)&Bs[((long)(b*KD + k)*NST + (c-6))*L_ + l]) = acc;
    else
      *((float4*)&Cs[((long)(b*KD + k)*NST + (c-22))*L_ + l]) = acc;
  }
}

// --------------------------------------------------------- K4: selective scan
// block = 128 threads = 8 groups(d) x 16 lanes(n); grid = (b,k,d-tile of 8)
__global__ __launch_bounds__(128) void k4_scan(
    const float* __restrict__ xc, const float* __restrict__ xT,
    const float* __restrict__ dts_low, const float* __restrict__ Bs_g,
    const float* __restrict__ Cs_g, const float* __restrict__ dtw_g,
    const float* __restrict__ dtb_g, const float* __restrict__ A_logs,
    const float* __restrict__ Ds_g, float* __restrict__ bufA,
    float* __restrict__ bufB) {
  const int bid = blockIdx.x;
  const int dt = bid % 24; const int k = (bid/24) & 3; const int b = bid / 96;
  const int d0 = dt * 8;
  const int t = threadIdx.x;
  const int g = t >> 4, nj = t & 15;            // nj: n in scan phase, j in load phase
  __shared__ float2 bc[2][16][17];              // [buf][j][n] = (B, C)
  __shared__ float2 du[2][8][17];               // [buf][g][j] = (delta, delta*u)
  __shared__ float  ut[2][8][17];               // [buf][g][j] = u
  __shared__ float  pt[8*328];                  // per-group 16x16 transpose, [g][n][j] stride 20

  const int d = d0 + g;
  const float a  = -__expf(A_logs[(k*DIN + d)*NST + nj]);
  const float Dv = Ds_g[k*DIN + d];
  float dtw[6];
  #pragma unroll
  for (int r = 0; r < 6; ++r) dtw[r] = dtw_g[(k*DIN + d)*RNK + r];
  const float dtbv = dtb_g[k*DIN + d];
  const float* src  = (k & 1) ? xT : xc;
  const bool flip = k >= 2;
  const float* Bsb  = Bs_g + (long)(b*KD + k)*NST*L_;
  const float* Csb  = Cs_g + (long)(b*KD + k)*NST*L_;
  const float* dtlb = dts_low + (long)(b*KD + k)*RNK*L_;
  const float* ub   = src + ((long)b*DIN + d)*L_;
  float* yb = ((k & 1) ? bufB : bufA) + (((long)b*2 + (k>>1))*DIN + d)*L_;

  auto load_chunk = [&](int c, int pbuf) {
    const int l0 = c*16;
    // B/C tile: thread (g, j=nj) loads n = g and g+8 at column j
    {
      float Bv = Bsb[g*L_ + l0 + nj];
      float Cv = Csb[g*L_ + l0 + nj];
      bc[pbuf][nj][g] = make_float2(Bv, Cv);
      Bv = Bsb[(g+8)*L_ + l0 + nj];
      Cv = Csb[(g+8)*L_ + l0 + nj];
      bc[pbuf][nj][g+8] = make_float2(Bv, Cv);
    }
    const int pos = flip ? (L_-1 - (l0+nj)) : (l0+nj);
    const float uu = ub[pos];
    float acc = dtbv;
    #pragma unroll
    for (int r = 0; r < 6; ++r) acc = fmaf(dtw[r], dtlb[r*L_ + l0 + nj], acc);
    const float dl = (acc > 20.f) ? acc : log1pf(__expf(acc));   // softplus
    du[pbuf][g][nj] = make_float2(dl, dl*uu);
    ut[pbuf][g][nj] = uu;
  };

  float h = 0.f;
  load_chunk(0, 0);
  for (int c = 0; c < L_/16; ++c) {
    __syncthreads();
    if (c + 1 < L_/16) load_chunk(c + 1, (c + 1) & 1);
    const int pb = c & 1;
    float p[16];
    #pragma unroll
    for (int j = 0; j < 16; ++j) {
      float2 dd  = du[pb][g][j];                // broadcast
      float2 bcv = bc[pb][j][nj];
      float dA = __expf(dd.x * a);
      h = fmaf(h, dA, dd.y * bcv.x);
      p[j] = h * bcv.y;
    }
    // wave-private 16x16 transpose: lane n banks p[j]; lane j sums over n
    #pragma unroll
    for (int q = 0; q < 4; ++q)
      *((float4*)&pt[g*328 + nj*20 + q*4]) = make_float4(p[q*4], p[q*4+1], p[q*4+2], p[q*4+3]);
    __builtin_amdgcn_wave_barrier();
    float y = 0.f;
    #pragma unroll
    for (int m = 0; m < 16; ++m) y += pt[g*328 + m*20 + nj];
    y = fmaf(Dv, ut[pb][g][nj], y);             // + D * u  (skip connection)
    const int l0 = c*16;
    const int pos = flip ? (L_-1 - (l0+nj)) : (l0+nj);
    yb[pos] = y;                                // coalesced 64B per group
  }
}

// ------------------------------------------------------------ K5a: cross-merge
// ym[b,l,d] = A0[l] + A1[l] + B0[m] + B1[m],  m = w*H + h for l = h*W + w
__global__ __launch_bounds__(256) void k5a_merge(
    const float* __restrict__ bufA, const float* __restrict__ bufB,
    float* __restrict__ ym) {
  const int bid = blockIdx.x;
  const int dc = bid % 6; const int tile = (bid/6) % 9; const int b = bid / 54;
  const int h0 = (tile/3)*16, w0 = (tile%3)*16, d0 = dc*32;
  __shared__ float acc[8644];                   // addr = h*541 + w*33 + d
  const int t = threadIdx.x;
  for (int idx = t; idx < 8192; idx += 256) {   // lanes along w (coalesced bufA)
    int w = idx & 15, hh = (idx >> 4) & 15, ds = idx >> 8;
    long pos = (long)(h0+hh)*W_ + w0 + w;
    float v = bufA[(((long)b*2 + 0)*DIN + d0+ds)*L_ + pos]
            + bufA[(((long)b*2 + 1)*DIN + d0+ds)*L_ + pos];
    acc[hh*541 + w*33 + ds] = v;
  }
  __syncthreads();
  for (int idx = t; idx < 8192; idx += 256) {   // lanes along h (coalesced bufB)
    int hh = idx & 15, w = (idx >> 4) & 15, ds = idx >> 8;
    long m = (long)(w0+w)*H_ + h0 + hh;
    float v = bufB[(((long)b*2 + 0)*DIN + d0+ds)*L_ + m]
            + bufB[(((long)b*2 + 1)*DIN + d0+ds)*L_ + m];
    acc[hh*541 + w*33 + ds] += v;
  }
  __syncthreads();
  for (int idx = t; idx < 8192; idx += 256) {   // lanes along d (coalesced write)
    int ds = idx & 31, w = (idx >> 5) & 15, hh = idx >> 9;
    ym[((long)b*L_ + (h0+hh)*W_ + w0+w)*DIN + d0 + ds] = acc[hh*541 + w*33 + ds];
  }
}

// ----------------------------------------- K5b: LayerNorm + gate + out_proj
__global__ __launch_bounds__(256) void k5b_out(
    const float* __restrict__ ym, const float* __restrict__ zs,
    const float* __restrict__ lnw, const float* __restrict__ lnb,
    const float* __restrict__ wo, float* __restrict__ out) {
  const int bid = blockIdx.x;
  const int ch = bid & 1; const int lt = (bid >> 1) % 72; const int b = bid / 144;
  const int l0 = lt * 32;
  const int c0 = ch * 48;
  __shared__ float yt[DIN*33];                  // [dd][l] padded (l-tile 32)
  __shared__ float wt[DIN*48];                  // [dd][cc], cc in c-half
  __shared__ float mu_s[32], rs_s[32];
  const int t = threadIdx.x;
  for (int idx = t; idx < 32*DIN; idx += 256) {
    int dd = idx % DIN, l = idx / DIN;
    yt[dd*33 + l] = ym[((long)b*L_ + l0 + l)*DIN + dd];
  }
  for (int idx = t; idx < DIN*48; idx += 256) {
    int cc = idx % 48, dd = idx / 48;
    wt[dd*48 + cc] = wo[(c0 + cc)*DIN + dd];
  }
  __syncthreads();
  {                                             // LN stats: 8 lanes per row
    int l = t >> 3, s = t & 7;
    float sum = 0.f, sq = 0.f;
    for (int dd = s; dd < DIN; dd += 8) {
      float v = yt[dd*33 + l]; sum += v; sq = fmaf(v, v, sq);
    }
    #pragma unroll
    for (int o = 1; o < 8; o <<= 1) { sum += __shfl_xor(sum, o, 64); sq += __shfl_xor(sq, o, 64); }
    if (s == 0) {
      float mu = sum * (1.f/192.f);
      mu_s[l] = mu;
      rs_s[l] = rsqrtf(fmaxf(sq * (1.f/192.f) - mu*mu, 0.f) + 1e-5f);
    }
  }
  __syncthreads();
  for (int idx = t; idx < 32*DIN; idx += 256) { // normalize + gate, in place
    int dd = idx % DIN, l = idx / DIN;
    float v = yt[dd*33 + l];
    v = (v - mu_s[l]) * rs_s[l] * lnw[dd] + lnb[dd];
    v *= zs[((long)b*L_ + l0 + l)*DIN + dd];
    yt[dd*33 + l] = v;
  }
  __syncthreads();
  for (int u = t; u < 24*16; u += 256) {        // unit = (c-pair, l-pair)
    int cp = u % 24, lp = u / 24;
    int cc = cp*2, l = lp*2;
    float a00=0.f, a01=0.f, a10=0.f, a11=0.f;
    for (int dd = 0; dd < DIN; ++dd) {
      float2 wv = *((const float2*)&wt[dd*48 + cc]);
      float2 yv = *((const float2*)&yt[dd*33 + l]);
      a00 = fmaf(wv.x, yv.x, a00); a01 = fmaf(wv.y, yv.x, a01);
      a10 = fmaf(wv.x, yv.y, a10); a11 = fmaf(wv.y, yv.y, a11);
    }
    long ob = ((long)b*L_ + l0 + l)*DM + c0 + cc;
    *((float2*)&out[ob])      = make_float2(a00, a01);
    *((float2*)&out[ob + DM]) = make_float2(a10, a11);
  }
}

// ------------------------------------------------------------------- launcher
extern "C" void kernel_launch(void* const* d_in, const int* in_sizes, int n_in,
                              void* d_out, int out_size, void* d_ws, size_t ws_size,
                              hipStream_t stream) {
  (void)in_sizes; (void)n_in; (void)out_size; (void)ws_size;
  const float* x      = (const float*)d_in[0];
  const float* w_in   = (const float*)d_in[1];
  const float* conv_w = (const float*)d_in[2];
  const float* conv_b = (const float*)d_in[3];
  const float* xpw    = (const float*)d_in[4];
  const float* dtw    = (const float*)d_in[5];
  const float* dtb    = (const float*)d_in[6];
  const float* A_logs = (const float*)d_in[7];
  const float* Ds     = (const float*)d_in[8];
  const float* lnw    = (const float*)d_in[9];
  const float* lnb    = (const float*)d_in[10];
  const float* wout   = (const float*)d_in[11];
  float* out = (float*)d_out;
  float* ws  = (float*)d_ws;

  const long SZ_BLD = (long)B_*L_*DIN;          // 3,538,944
  float* xc_pre  = ws;                          // (B,L,Din)     [aliased by ym later]
  float* z_silu  = ws + SZ_BLD;                 // (B,L,Din)
  float* xc      = ws + 2*SZ_BLD;               // (B,Din,L)
  float* xT      = ws + 3*SZ_BLD;               // (B,Din,L) col-major traversal
  float* dts_low = ws + 4*SZ_BLD;               // (B,K,R,L)    442,368
  float* Bs      = dts_low + (long)B_*KD*RNK*L_;      // (B,K,N,L) 1,179,648
  float* Cs      = Bs + (long)B_*KD*NST*L_;
  float* bufA    = Cs + (long)B_*KD*NST*L_;     // (B,2,Din,L)  7,077,888
  float* bufB    = bufA + (long)B_*2*DIN*L_;
  float* ym      = xc_pre;                      // alias: xc_pre dead after K2

  k1_inproj<<<(B_*L_)/16, 256, 0, stream>>>(x, w_in, xc_pre, z_silu);
  k2_conv  <<<B_*6*9,    256, 0, stream>>>(xc_pre, conv_w, conv_b, xc, xT);
  k3_xdbl  <<<B_*KD*72,  256, 0, stream>>>(xc, xT, xpw, dts_low, Bs, Cs);
  k4_scan  <<<B_*KD*24,  128, 0, stream>>>(xc, xT, dts_low, Bs, Cs, dtw, dtb,
                                           A_logs, Ds, bufA, bufB);
  k5a_merge<<<B_*9*6,    256, 0, stream>>>(bufA, bufB, ym);
  k5b_out  <<<B_*72*2,   256, 0, stream>>>(ym, z_silu, lnw, lnb, wout, out);
}

// Round 2
// 501.571 us; speedup vs baseline: 1.0084x; 1.0084x over previous
//
#include <hip/hip_runtime.h>
#include <hip/hip_bf16.h>

// SS2D fused pipeline for MI355X (gfx950). All fp32.
// K1 in_proj(+silu z) -> K2 dwconv3x3+silu(+transposed copy) -> K3 x_dbl proj
// -> K4a chunk-local scan carries -> K4b carry combine -> K4c full scan
// -> K5a cross-merge -> K5b LayerNorm+gate+out_proj.

#define B_   8
#define H_   48
#define W_   48
#define DM   96
#define DIN  192
#define NST  16
#define RNK  6
#define KD   4
#define L_   (H_*W_)      // 2304
#define NCH  6
#define LC   (L_/NCH)     // 384 = 24 sub-chunks of 16

// ---------------------------------------------------------------- K1: in_proj
__global__ __launch_bounds__(256) void k1_inproj(
    const float* __restrict__ x, const float* __restrict__ w,
    float* __restrict__ xc_pre, float* __restrict__ z_silu) {
  __shared__ float xs[16][100];
  const int t = threadIdx.x;
  const long row0 = (long)blockIdx.x * 16;
  for (int idx = t; idx < 16*96; idx += 256) {
    int r = idx / 96, c = idx % 96;
    xs[r][c] = x[(row0 + r)*96 + c];
  }
  __syncthreads();
  for (int u = t; u < 2*DIN; u += 256) {
    float acc[16];
    #pragma unroll
    for (int r = 0; r < 16; ++r) acc[r] = 0.f;
    const float4* wrow = (const float4*)(w + u*96);
    #pragma unroll 4
    for (int cq = 0; cq < 24; ++cq) {
      float4 w4 = wrow[cq];
      #pragma unroll
      for (int r = 0; r < 16; ++r) {
        float4 x4 = *((const float4*)&xs[r][cq*4]);
        acc[r] = fmaf(w4.x,x4.x, fmaf(w4.y,x4.y, fmaf(w4.z,x4.z, fmaf(w4.w,x4.w, acc[r]))));
      }
    }
    if (u < DIN) {
      #pragma unroll
      for (int r = 0; r < 16; ++r) xc_pre[(row0 + r)*DIN + u] = acc[r];
    } else {
      #pragma unroll
      for (int r = 0; r < 16; ++r) {
        float v = acc[r];
        z_silu[(row0 + r)*DIN + (u - DIN)] = v / (1.f + __expf(-v));
      }
    }
  }
}

// ------------------------------------------------- K2: depthwise conv + silu
// 8 barriers/block (per-octet transpose) instead of 64.
__global__ __launch_bounds__(256) void k2_conv(
    const float* __restrict__ xc_pre, const float* __restrict__ cw,
    const float* __restrict__ cb, float* __restrict__ xc, float* __restrict__ xT) {
  const int bid = blockIdx.x;
  const int tile = bid % 9; const int dc = (bid/9) % 6; const int b = bid / 54;
  const int h0 = (tile/3)*16, w0 = (tile%3)*16, d0 = dc*32;
  __shared__ float tin[32*325];
  __shared__ float tout[8][16][17];
  const int t = threadIdx.x;
  for (int idx = t; idx < 32*18*18; idx += 256) {
    int d2 = idx & 31; int rest = idx >> 5; int ww = rest % 18; int hh = rest / 18;
    int h = h0 + hh - 1, w = w0 + ww - 1;
    float v = 0.f;
    if (h >= 0 && h < H_ && w >= 0 && w < W_)
      v = xc_pre[((long)b*L_ + h*W_ + w)*DIN + d0 + d2];
    tin[d2*325 + hh*18 + ww] = v;
  }
  __syncthreads();
  const int hh = t >> 4, ww = t & 15;
  for (int oct = 0; oct < 4; ++oct) {
    #pragma unroll
    for (int q = 0; q < 8; ++q) {
      const int d2 = oct*8 + q;
      const int d = d0 + d2;
      float acc = cb[d];
      const float* k9 = &cw[d*9];
      const float* base = &tin[d2*325];
      #pragma unroll
      for (int i = 0; i < 3; ++i)
        #pragma unroll
        for (int j = 0; j < 3; ++j)
          acc = fmaf(base[(hh+i)*18 + ww + j], k9[i*3+j], acc);
      float s = acc / (1.f + __expf(-acc));
      xc[((long)b*DIN + d)*L_ + (h0+hh)*W_ + w0 + ww] = s;
      tout[q][hh][ww] = s;
    }
    __syncthreads();
    #pragma unroll
    for (int q = 0; q < 8; ++q) {
      const int d = d0 + oct*8 + q;
      float s2 = tout[q][t & 15][t >> 4];
      xT[((long)b*DIN + d)*L_ + (w0 + (t>>4))*H_ + h0 + (t & 15)] = s2;
    }
    __syncthreads();
  }
}

// ----------------------------------------------------------- K3: x_dbl proj
__global__ __launch_bounds__(256) void k3_xdbl(
    const float* __restrict__ xc, const float* __restrict__ xT,
    const float* __restrict__ xpw, float* __restrict__ dts_low,
    float* __restrict__ Bs, float* __restrict__ Cs) {
  const int bid = blockIdx.x;
  const int lt = bid % 72; const int k = (bid/72) & 3; const int b = bid / 288;
  const int l0 = lt * 32;
  __shared__ float xtile[DIN*32];
  __shared__ float wl[38*193];
  const float* src = (k & 1) ? xT : xc;
  const bool flip = k >= 2;
  const int t = threadIdx.x;
  for (int idx = t; idx < DIN*32; idx += 256) {
    int d = idx >> 5, j = idx & 31;
    int pos = flip ? (L_-1 - (l0+j)) : (l0+j);
    xtile[d*32 + j] = src[((long)b*DIN + d)*L_ + pos];
  }
  for (int idx = t; idx < 38*DIN; idx += 256) {
    int c = idx / DIN, d = idx % DIN;
    wl[c*193 + d] = xpw[(k*38 + c)*DIN + d];
  }
  __syncthreads();
  for (int u = t; u < 38*8; u += 256) {
    int jq = u & 7, c = u >> 3;
    float4 acc = {0.f,0.f,0.f,0.f};
    for (int d = 0; d < DIN; ++d) {
      float wv = wl[c*193 + d];
      float4 x4 = *((const float4*)&xtile[d*32 + jq*4]);
      acc.x = fmaf(wv, x4.x, acc.x); acc.y = fmaf(wv, x4.y, acc.y);
      acc.z = fmaf(wv, x4.z, acc.z); acc.w = fmaf(wv, x4.w, acc.w);
    }
    const int l = l0 + jq*4;
    if (c < 6)
      *((float4*)&dts_low[((long)(b*KD + k)*RNK + c)*L_ + l]) = acc;
    else if (c < 22)
      *((float4*)&Bs[((long)(b*KD + k)*NST + (c-6))*L_ + l]) = acc;
    else
      *((float4*)&Cs[((long)(b*KD + k)*NST + (c-22))*L_ + l]) = acc;
  }
}

// --------------------------------------------- K4a: chunk-local scan carries
// block = 128 thr = 8 d-groups x 16 n-lanes; grid = (b,k,dtile,chunk)
__global__ __launch_bounds__(128, 8) void k4a_carry(
    const float* __restrict__ xc, const float* __restrict__ xT,
    const float* __restrict__ dts_low, const float* __restrict__ Bs_g,
    const float* __restrict__ dtw_g, const float* __restrict__ dtb_g,
    const float* __restrict__ A_logs, float* __restrict__ carryH,
    float* __restrict__ carryP) {
  const int bid = blockIdx.x;
  const int cc = bid % NCH; const int rest = bid / NCH;
  const int dt = rest % 24; const int k = (rest/24) & 3; const int b = rest / 96;
  const int d0 = dt * 8;
  const int t = threadIdx.x;
  const int g = t >> 4, nj = t & 15;
  __shared__ float  Bt[2][16][17];
  __shared__ float2 du[2][8][17];

  const int d = d0 + g;
  const float a = -__expf(A_logs[(k*DIN + d)*NST + nj]);
  float dtw[6];
  #pragma unroll
  for (int r = 0; r < 6; ++r) dtw[r] = dtw_g[(k*DIN + d)*RNK + r];
  const float dtbv = dtb_g[k*DIN + d];
  const float* src  = (k & 1) ? xT : xc;
  const bool flip = k >= 2;
  const float* Bsb  = Bs_g + (long)(b*KD + k)*NST*L_;
  const float* dtlb = dts_low + (long)(b*KD + k)*RNK*L_;
  const float* ub   = src + ((long)b*DIN + d)*L_;
  const int base = cc * LC;

  auto load_chunk = [&](int c2, int pbuf) {
    const int l0 = base + c2*16;
    Bt[pbuf][nj][g]   = Bsb[g*L_ + l0 + nj];
    Bt[pbuf][nj][g+8] = Bsb[(g+8)*L_ + l0 + nj];
    const int pos = flip ? (L_-1 - (l0+nj)) : (l0+nj);
    const float uu = ub[pos];
    float acc = dtbv;
    #pragma unroll
    for (int r = 0; r < 6; ++r) acc = fmaf(dtw[r], dtlb[r*L_ + l0 + nj], acc);
    const float dl = (acc > 20.f) ? acc : log1pf(__expf(acc));
    du[pbuf][g][nj] = make_float2(dl, dl*uu);
  };

  float h = 0.f, prod = 1.f;
  load_chunk(0, 0);
  for (int c2 = 0; c2 < LC/16; ++c2) {
    __syncthreads();
    if (c2 + 1 < LC/16) load_chunk(c2 + 1, (c2 + 1) & 1);
    const int pb = c2 & 1;
    #pragma unroll
    for (int j = 0; j < 16; ++j) {
      float2 dd = du[pb][g][j];
      float Bv  = Bt[pb][j][nj];
      float dA = __expf(dd.x * a);
      h = fmaf(h, dA, dd.y * Bv);
      prod *= dA;
    }
  }
  const long s = (long)(b*KD + k)*DIN + d;
  carryH[(s*NCH + cc)*16 + nj] = h;
  carryP[(s*NCH + cc)*16 + nj] = prod;
}

// ------------------------------------------------------ K4b: combine carries
// in-place: carryH[s][c][n] becomes h_in for chunk c
__global__ __launch_bounds__(256) void k4b_combine(
    float* __restrict__ carryH, const float* __restrict__ carryP) {
  const int tid = blockIdx.x*256 + threadIdx.x;   // < 6144*16
  const int n = tid & 15; const long s = tid >> 4;
  float h = 0.f;
  #pragma unroll
  for (int c = 0; c < NCH; ++c) {
    const long idx = (s*NCH + c)*16 + n;
    const float ho = carryH[idx];
    const float ap = carryP[idx];
    carryH[idx] = h;
    h = fmaf(h, ap, ho);
  }
}

// ----------------------------------------------------- K4c: full scan + y-out
__global__ __launch_bounds__(128, 6) void k4c_scan(
    const float* __restrict__ xc, const float* __restrict__ xT,
    const float* __restrict__ dts_low, const float* __restrict__ Bs_g,
    const float* __restrict__ Cs_g, const float* __restrict__ dtw_g,
    const float* __restrict__ dtb_g, const float* __restrict__ A_logs,
    const float* __restrict__ Ds_g, const float* __restrict__ carryH,
    float* __restrict__ bufA, float* __restrict__ bufB) {
  const int bid = blockIdx.x;
  const int cc = bid % NCH; const int rest = bid / NCH;
  const int dt = rest % 24; const int k = (rest/24) & 3; const int b = rest / 96;
  const int d0 = dt * 8;
  const int t = threadIdx.x;
  const int g = t >> 4, nj = t & 15;
  __shared__ float2 bc[2][16][17];              // [buf][j][n] = (B, C)
  __shared__ float2 du[2][8][17];               // [buf][g][j] = (delta, delta*u)
  __shared__ float  ut[2][8][17];               // [buf][g][j] = u

  const int d = d0 + g;
  const float a  = -__expf(A_logs[(k*DIN + d)*NST + nj]);
  const float Dv = Ds_g[k*DIN + d];
  float dtw[6];
  #pragma unroll
  for (int r = 0; r < 6; ++r) dtw[r] = dtw_g[(k*DIN + d)*RNK + r];
  const float dtbv = dtb_g[k*DIN + d];
  const float* src  = (k & 1) ? xT : xc;
  const bool flip = k >= 2;
  const float* Bsb  = Bs_g + (long)(b*KD + k)*NST*L_;
  const float* Csb  = Cs_g + (long)(b*KD + k)*NST*L_;
  const float* dtlb = dts_low + (long)(b*KD + k)*RNK*L_;
  const float* ub   = src + ((long)b*DIN + d)*L_;
  float* yb = ((k & 1) ? bufB : bufA) + (((long)b*2 + (k>>1))*DIN + d)*L_;
  const long s = (long)(b*KD + k)*DIN + d;
  const int base = cc * LC;

  auto load_chunk = [&](int c2, int pbuf) {
    const int l0 = base + c2*16;
    {
      float Bv = Bsb[g*L_ + l0 + nj];
      float Cv = Csb[g*L_ + l0 + nj];
      bc[pbuf][nj][g] = make_float2(Bv, Cv);
      Bv = Bsb[(g+8)*L_ + l0 + nj];
      Cv = Csb[(g+8)*L_ + l0 + nj];
      bc[pbuf][nj][g+8] = make_float2(Bv, Cv);
    }
    const int pos = flip ? (L_-1 - (l0+nj)) : (l0+nj);
    const float uu = ub[pos];
    float acc = dtbv;
    #pragma unroll
    for (int r = 0; r < 6; ++r) acc = fmaf(dtw[r], dtlb[r*L_ + l0 + nj], acc);
    const float dl = (acc > 20.f) ? acc : log1pf(__expf(acc));
    du[pbuf][g][nj] = make_float2(dl, dl*uu);
    ut[pbuf][g][nj] = uu;
  };

  float h = carryH[(s*NCH + cc)*16 + nj];       // chunk-entry state
  load_chunk(0, 0);
  for (int c2 = 0; c2 < LC/16; ++c2) {
    __syncthreads();
    if (c2 + 1 < LC/16) load_chunk(c2 + 1, (c2 + 1) & 1);
    const int pb = c2 & 1;
    float p[16];
    #pragma unroll
    for (int j = 0; j < 16; ++j) {
      float2 dd  = du[pb][g][j];
      float2 bcv = bc[pb][j][nj];
      float dA = __expf(dd.x * a);
      h = fmaf(h, dA, dd.y * bcv.x);
      p[j] = h * bcv.y;
    }
    // register butterfly: transpose 16x16 across the 16-lane group + sum.
    // After step kk, p[ii] corresponds to time-index (ii<<(kk+1)) | (nj & mask)
    #pragma unroll
    for (int kk = 0; kk < 4; ++kk) {
      const int m = 1 << kk;
      const bool bb = (nj & m) != 0;
      #pragma unroll
      for (int ii = 0; ii < (16 >> (kk+1)); ++ii) {
        float x0 = p[2*ii], x1 = p[2*ii+1];
        float send = bb ? x0 : x1;
        float keep = bb ? x1 : x0;
        p[ii] = keep + __shfl_xor(send, m, 64);
      }
    }
    float y = fmaf(Dv, ut[pb][g][nj], p[0]);
    const int l0 = base + c2*16;
    const int pos = flip ? (L_-1 - (l0+nj)) : (l0+nj);
    yb[pos] = y;
  }
}

// ------------------------------------------------------------ K5a: cross-merge
__global__ __launch_bounds__(256) void k5a_merge(
    const float* __restrict__ bufA, const float* __restrict__ bufB,
    float* __restrict__ ym) {
  const int bid = blockIdx.x;
  const int dc = bid % 6; const int tile = (bid/6) % 9; const int b = bid / 54;
  const int h0 = (tile/3)*16, w0 = (tile%3)*16, d0 = dc*32;
  __shared__ float acc[8644];
  const int t = threadIdx.x;
  for (int idx = t; idx < 8192; idx += 256) {
    int w = idx & 15, hh = (idx >> 4) & 15, ds = idx >> 8;
    long pos = (long)(h0+hh)*W_ + w0 + w;
    float v = bufA[(((long)b*2 + 0)*DIN + d0+ds)*L_ + pos]
            + bufA[(((long)b*2 + 1)*DIN + d0+ds)*L_ + pos];
    acc[hh*541 + w*33 + ds] = v;
  }
  __syncthreads();
  for (int idx = t; idx < 8192; idx += 256) {
    int hh = idx & 15, w = (idx >> 4) & 15, ds = idx >> 8;
    long m = (long)(w0+w)*H_ + h0 + hh;
    float v = bufB[(((long)b*2 + 0)*DIN + d0+ds)*L_ + m]
            + bufB[(((long)b*2 + 1)*DIN + d0+ds)*L_ + m];
    acc[hh*541 + w*33 + ds] += v;
  }
  __syncthreads();
  for (int idx = t; idx < 8192; idx += 256) {
    int ds = idx & 31, w = (idx >> 5) & 15, hh = idx >> 9;
    ym[((long)b*L_ + (h0+hh)*W_ + w0+w)*DIN + d0 + ds] = acc[hh*541 + w*33 + ds];
  }
}

// ----------------------------------------- K5b: LayerNorm + gate + out_proj
__global__ __launch_bounds__(256) void k5b_out(
    const float* __restrict__ ym, const float* __restrict__ zs,
    const float* __restrict__ lnw, const float* __restrict__ lnb,
    const float* __restrict__ wo, float* __restrict__ out) {
  const int bid = blockIdx.x;
  const int ch = bid & 1; const int lt = (bid >> 1) % 72; const int b = bid / 144;
  const int l0 = lt * 32;
  const int c0 = ch * 48;
  __shared__ float yt[DIN*33];
  __shared__ float wt[DIN*48];
  __shared__ float mu_s[32], rs_s[32];
  const int t = threadIdx.x;
  for (int idx = t; idx < 32*DIN; idx += 256) {
    int dd = idx % DIN, l = idx / DIN;
    yt[dd*33 + l] = ym[((long)b*L_ + l0 + l)*DIN + dd];
  }
  for (int idx = t; idx < DIN*48; idx += 256) {
    int cc = idx % 48, dd = idx / 48;
    wt[dd*48 + cc] = wo[(c0 + cc)*DIN + dd];
  }
  __syncthreads();
  {
    int l = t >> 3, s = t & 7;
    float sum = 0.f, sq = 0.f;
    for (int dd = s; dd < DIN; dd += 8) {
      float v = yt[dd*33 + l]; sum += v; sq = fmaf(v, v, sq);
    }
    #pragma unroll
    for (int o = 1; o < 8; o <<= 1) { sum += __shfl_xor(sum, o, 64); sq += __shfl_xor(sq, o, 64); }
    if (s == 0) {
      float mu = sum * (1.f/192.f);
      mu_s[l] = mu;
      rs_s[l] = rsqrtf(fmaxf(sq * (1.f/192.f) - mu*mu, 0.f) + 1e-5f);
    }
  }
  __syncthreads();
  for (int idx = t; idx < 32*DIN; idx += 256) {
    int dd = idx % DIN, l = idx / DIN;
    float v = yt[dd*33 + l];
    v = (v - mu_s[l]) * rs_s[l] * lnw[dd] + lnb[dd];
    v *= zs[((long)b*L_ + l0 + l)*DIN + dd];
    yt[dd*33 + l] = v;
  }
  __syncthreads();
  for (int u = t; u < 24*16; u += 256) {
    int cp = u % 24, lp = u / 24;
    int cc = cp*2, l = lp*2;
    float a00=0.f, a01=0.f, a10=0.f, a11=0.f;
    for (int dd = 0; dd < DIN; ++dd) {
      float2 wv = *((const float2*)&wt[dd*48 + cc]);
      float2 yv = *((const float2*)&yt[dd*33 + l]);
      a00 = fmaf(wv.x, yv.x, a00); a01 = fmaf(wv.y, yv.x, a01);
      a10 = fmaf(wv.x, yv.y, a10); a11 = fmaf(wv.y, yv.y, a11);
    }
    long ob = ((long)b*L_ + l0 + l)*DM + c0 + cc;
    *((float2*)&out[ob])      = make_float2(a00, a01);
    *((float2*)&out[ob + DM]) = make_float2(a10, a11);
  }
}

// ------------------------------------------------------------------- launcher
extern "C" void kernel_launch(void* const* d_in, const int* in_sizes, int n_in,
                              void* d_out, int out_size, void* d_ws, size_t ws_size,
                              hipStream_t stream) {
  (void)in_sizes; (void)n_in; (void)out_size; (void)ws_size;
  const float* x      = (const float*)d_in[0];
  const float* w_in   = (const float*)d_in[1];
  const float* conv_w = (const float*)d_in[2];
  const float* conv_b = (const float*)d_in[3];
  const float* xpw    = (const float*)d_in[4];
  const float* dtw    = (const float*)d_in[5];
  const float* dtb    = (const float*)d_in[6];
  const float* A_logs = (const float*)d_in[7];
  const float* Ds     = (const float*)d_in[8];
  const float* lnw    = (const float*)d_in[9];
  const float* lnb    = (const float*)d_in[10];
  const float* wout   = (const float*)d_in[11];
  float* out = (float*)d_out;
  float* ws  = (float*)d_ws;

  const long SZ_BLD = (long)B_*L_*DIN;          // 3,538,944
  float* xc_pre  = ws;                          // (B,L,Din)  [reused: carries, then ym]
  float* z_silu  = ws + SZ_BLD;
  float* xc      = ws + 2*SZ_BLD;
  float* xT      = ws + 3*SZ_BLD;
  float* dts_low = ws + 4*SZ_BLD;
  float* Bs      = dts_low + (long)B_*KD*RNK*L_;
  float* Cs      = Bs + (long)B_*KD*NST*L_;
  float* bufA    = Cs + (long)B_*KD*NST*L_;     // (B,2,Din,L)
  float* bufB    = bufA + (long)B_*2*DIN*L_;
  // carry buffers alias xc_pre (dead after K2); ym aliases it after K4c.
  float* carryH  = xc_pre;                      // 6144*NCH*16 = 589,824 floats
  float* carryP  = xc_pre + (long)6144*NCH*16;
  float* ym      = xc_pre;

  k1_inproj  <<<(B_*L_)/16,    256, 0, stream>>>(x, w_in, xc_pre, z_silu);
  k2_conv    <<<B_*6*9,        256, 0, stream>>>(xc_pre, conv_w, conv_b, xc, xT);
  k3_xdbl    <<<B_*KD*72,      256, 0, stream>>>(xc, xT, xpw, dts_low, Bs, Cs);
  k4a_carry  <<<B_*KD*24*NCH,  128, 0, stream>>>(xc, xT, dts_low, Bs, dtw, dtb,
                                                 A_logs, carryH, carryP);
  k4b_combine<<<(6144*16)/256, 256, 0, stream>>>(carryH, carryP);
  k4c_scan   <<<B_*KD*24*NCH,  128, 0, stream>>>(xc, xT, dts_low, Bs, Cs, dtw, dtb,
                                                 A_logs, Ds, carryH, bufA, bufB);
  k5a_merge  <<<B_*9*6,        256, 0, stream>>>(bufA, bufB, ym);
  k5b_out    <<<B_*72*2,       256, 0, stream>>>(ym, z_silu, lnw, lnb, wout, out);
}